// Round 15
// baseline (404.245 us; speedup 1.0000x reference)
//
#include <hip/hip_runtime.h>

typedef _Float16 half8 __attribute__((ext_vector_type(8)));
typedef _Float16 half4 __attribute__((ext_vector_type(4)));
typedef _Float16 half2v __attribute__((ext_vector_type(2)));
typedef float f32x4 __attribute__((ext_vector_type(4)));

#define IN_F 4096
#define OUT_F 4096
#define NROWS 4096   // B*S
#define NBLK 64
#define BIN 512
#define BOUT 512
#define NPAIR (NBLK * BOUT)   // 32768 (n,o) pairs

__device__ __forceinline__ void gload16(const void* g, void* l) {
    typedef __attribute__((address_space(1))) const void gvoid;
    typedef __attribute__((address_space(3))) void lvoid;
    __builtin_amdgcn_global_load_lds((gvoid*)g, (lvoid*)l, 16, 0, 0);
}

// ---------- setup kernels ----------

__global__ void detect_stride_k(const int* __restrict__ iin, int* __restrict__ flag) {
    int v = iin[threadIdx.x * 2 + 1];
    unsigned long long b = __ballot(v != 0);
    if (threadIdx.x == 0) flag[0] = (b == 0ULL) ? 2 : 1;
}

__global__ void cvt_w16_k(const float* __restrict__ w, _Float16* __restrict__ w16) {
    int i = (blockIdx.x * 256 + threadIdx.x) * 4;
    f32x4 v = *(const f32x4*)(w + i);
    half4 h;
    h[0] = (_Float16)v[0]; h[1] = (_Float16)v[1];
    h[2] = (_Float16)v[2]; h[3] = (_Float16)v[3];
    *(half4*)(w16 + i) = h;
}

// x[s][c] f32 -> xT16[c][s] f16
__global__ __launch_bounds__(256) void transpose_x_k(
    const float* __restrict__ x, _Float16* __restrict__ xT16)
{
    __shared__ float tile[64][65];
    const int c0 = blockIdx.x * 64, s0 = blockIdx.y * 64;
    const int t = threadIdx.x;
    {
        int s = t >> 4, c4 = (t & 15) * 4;
        #pragma unroll
        for (int p = 0; p < 4; ++p) {
            int ss = s + p * 16;
            f32x4 v = *(const f32x4*)(x + (size_t)(s0 + ss) * IN_F + c0 + c4);
            tile[ss][c4 + 0] = v[0]; tile[ss][c4 + 1] = v[1];
            tile[ss][c4 + 2] = v[2]; tile[ss][c4 + 3] = v[3];
        }
    }
    __syncthreads();
    {
        int c = t >> 3, s8 = (t & 7) * 8;
        #pragma unroll
        for (int p = 0; p < 2; ++p) {
            int cc = c + p * 32;
            half8 v;
            #pragma unroll
            for (int q = 0; q < 8; ++q) v[q] = (_Float16)tile[s8 + q][cc];
            *(half8*)(xT16 + (size_t)(c0 + cc) * NROWS + s0 + s8) = v;
        }
    }
}

// ---------- inverse-index build ----------

__global__ void count_k(const int* __restrict__ iout, const int* __restrict__ flag,
                        int* __restrict__ cnt) {
    int i = blockIdx.x * 256 + threadIdx.x;
    int c = iout[(size_t)i * flag[0]];
    atomicAdd(&cnt[c], 1);
}

__global__ __launch_bounds__(256) void scan_k(const int* __restrict__ cnt,
                                              int* __restrict__ off, int* __restrict__ cur) {
    __shared__ int sums[256];
    const int t = threadIdx.x;
    const int base = t * 16;
    int loc[16];
    int s = 0;
    #pragma unroll
    for (int i = 0; i < 16; ++i) { loc[i] = s; s += cnt[base + i]; }
    sums[t] = s;
    __syncthreads();
    for (int d = 1; d < 256; d <<= 1) {
        int v = (t >= d) ? sums[t - d] : 0;
        __syncthreads();
        sums[t] += v;
        __syncthreads();
    }
    int excl = sums[t] - s;
    #pragma unroll
    for (int i = 0; i < 16; ++i) {
        int o = excl + loc[i];
        off[base + i] = o;
        cur[base + i] = o;
    }
    if (t == 255) off[4096] = sums[255];
}

__global__ void fill_k(const int* __restrict__ iout, const int* __restrict__ flag,
                       int* __restrict__ cur, int* __restrict__ ent) {
    int i = blockIdx.x * 256 + threadIdx.x;
    int c = iout[(size_t)i * flag[0]];
    int pos = atomicAdd(&cur[c], 1);
    ent[pos] = i;
}

// ---------- fused gather + dense GEMM ----------
// yb[n*512+o][s_loc] = sum_k xT16[iin[n][k]][slab0+s_loc] * w16[n][o][k]
// 256(s) x 256(o) tile, BK=64, 8 waves, double-buffered 128 KiB LDS.
// DEEP GATHER PREFETCH: A-loads for tile ks+2 issued one iteration early;
// raw s_barrier with per-wave-group counted waits so the in-flight register
// gather loads are NOT drained at the barrier (full-iteration latency budget).
// A/B LDS addressing, compute, epilogue identical to r12/r14 (verified).
template<int SLAB>
__global__ __launch_bounds__(512, 2) void gemm_fused_k(
    const _Float16* __restrict__ xT16, const _Float16* __restrict__ w16,
    const int* __restrict__ iin, const int* __restrict__ flag,
    int slab0, _Float16* __restrict__ yb)
{
    __shared__ __align__(1024) _Float16 As[2][256 * 64];   // 2 x 32 KiB
    __shared__ __align__(1024) _Float16 Bs[2][256 * 64];   // 2 x 32 KiB
    __shared__ int kidx[BIN];

    const int t = threadIdx.x;
    const int bid = blockIdx.x;
    constexpr int MT4 = SLAB / 256;
    const int xcd = bid & 7;
    const int r = bid >> 3;
    const int mt = r % MT4;
    const int ot = (r / MT4) & 1;
    const int ng = r / (MT4 * 2);
    const int n = ng * 8 + xcd;                 // n == xcd (mod 8): panels L2-resident
    const int sl0 = mt * 256;                   // slab-local s base (for yb)
    const int sA = slab0 + sl0;                 // absolute s (for xT16)
    const int o0 = ot * 256;

    const int lane = t & 63, wid = t >> 6;      // 8 waves: 2(s) x 4(o) for compute
    const int wr = wid >> 2, wc = wid & 3;
    const int lr = lane & 15, lh = lane >> 4;

    char* Asb = (char*)As;
    char* Bsb = (char*)Bs;

    // load all 512 gather indices once
    kidx[t] = iin[((size_t)n * BIN + t) * flag[0]];
    __syncthreads();

    // A-transposer geometry (waves 0-3, t<256): 2 cols (k=2p,2p+1) x 32 s per thread
    const int p = t & 31;                        // k-pair index 0..31
    const int sb = (t >> 5) & 7;                 // s-block of 32: 0..7
    const _Float16* xsrc = xT16 + sA + sb * 32;
    // B-stager geometry (waves 4-7): u = t&255, 8 gload16 each
    const int u = t & 255;

    // load 2 gathered columns, 32 contiguous s each (one full 64B line per col)
    auto A_LOAD = [&](int ks, half8 v[2][4]) {
        const int c0 = kidx[ks * 64 + 2 * p];
        const int c1 = kidx[ks * 64 + 2 * p + 1];
        const _Float16* s0p = xsrc + (size_t)c0 * NROWS;
        const _Float16* s1p = xsrc + (size_t)c1 * NROWS;
        #pragma unroll
        for (int q = 0; q < 4; ++q) {
            v[0][q] = *(const half8*)(s0p + q * 8);
            v[1][q] = *(const half8*)(s1p + q * 8);
        }
    };
    // transpose and write: s = sb*32 + q*8 + rr, cols k=2p (lo) / 2p+1 (hi) packed.
    // byte = s*128 + ((slot ^ (s&7))<<4) + (k&7)*2, slot = k>>3  [r12-verified]
    auto A_WRITE = [&](int buf, half8 v[2][4]) {
        const int slot = p >> 2;
        const int ib = ((2 * p) & 7) * 2;        // byte offset inside 16B slot
        #pragma unroll
        for (int q = 0; q < 4; ++q)
            #pragma unroll
            for (int rr = 0; rr < 8; ++rr) {
                int s = sb * 32 + q * 8 + rr;
                half2v wv = {v[0][q][rr], v[1][q][rr]};
                *(half2v*)(Asb + buf * 32768 + s * 128 +
                           ((slot ^ (s & 7)) << 4) + ib) = wv;
            }
    };
    auto B_STAGE = [&](int buf, int ks) {
        const int k0 = ks * 64;
        #pragma unroll
        for (int j = 0; j < 8; ++j) {
            int sid = u + j * 256;               // 0..2047
            int row = sid >> 3, sl = sid & 7;
            const char* src = (const char*)(w16 + ((size_t)n * BOUT + o0 + row) * BIN + k0)
                              + ((sl ^ (row & 7)) << 4);
            gload16(src, Bsb + buf * 32768 + sid * 16);
        }
    };

    f32x4 acc[8][4];
    #pragma unroll
    for (int i = 0; i < 8; ++i)
        #pragma unroll
        for (int j = 0; j < 4; ++j) acc[i][j] = (f32x4){0.f, 0.f, 0.f, 0.f};

    constexpr int NT = BIN / 64;   // 8 k-tiles

    half8 v[2][4];   // persistent register gather buffer (A-waves)

    // prologue: tile0 staged; tile1's A-loads issued and left in flight
    if (wid < 4) {
        A_LOAD(0, v);
        A_WRITE(0, v);                 // compiler inserts vmcnt wait for v
        if (NT > 1) A_LOAD(1, v);      // deep prefetch: stays outstanding
        asm volatile("s_waitcnt lgkmcnt(0)" ::: "memory");
    } else {
        B_STAGE(0, 0);
        asm volatile("s_waitcnt vmcnt(0) lgkmcnt(0)" ::: "memory");
    }
    __builtin_amdgcn_s_barrier();

    for (int ks = 0; ks < NT; ++ks) {
        const int cur = ks & 1;
        const int curo = cur * 32768;
        const int nxt = cur ^ 1;

        // B-waves: issue next tile's LDS loads before compute
        if (wid >= 4 && ks < NT - 1) B_STAGE(nxt, ks + 1);

        // compute current tile (identical to verified r12/r14)
        #pragma unroll
        for (int kk = 0; kk < 2; ++kk) {
            half8 a[8], b[4];
            #pragma unroll
            for (int fm = 0; fm < 8; ++fm) {
                int srow = wr * 128 + fm * 16 + lr;
                a[fm] = *(const half8*)(Asb + curo + srow * 128 +
                                        (((kk * 4 + lh) ^ (srow & 7)) << 4));
            }
            #pragma unroll
            for (int fn = 0; fn < 4; ++fn) {
                int orow = wc * 64 + fn * 16 + lr;
                b[fn] = *(const half8*)(Bsb + curo + orow * 128 +
                                        (((kk * 4 + lh) ^ (orow & 7)) << 4));
            }
            __builtin_amdgcn_s_setprio(1);
            #pragma unroll
            for (int fm = 0; fm < 8; ++fm)
                #pragma unroll
                for (int fn = 0; fn < 4; ++fn)
                    acc[fm][fn] = __builtin_amdgcn_mfma_f32_16x16x32_f16(
                        a[fm], b[fn], acc[fm][fn], 0, 0, 0);
            __builtin_amdgcn_s_setprio(0);
        }

        // A-waves: write tile ks+1 (loaded one iteration ago -> latency amortized),
        // then issue tile ks+2's loads (WAR on v orders write-before-load).
        if (wid < 4) {
            if (ks < NT - 1) A_WRITE(nxt, v);
            if (ks < NT - 2) A_LOAD(ks + 2, v);
            asm volatile("s_waitcnt lgkmcnt(0)" ::: "memory");   // ds_writes visible
        } else {
            asm volatile("s_waitcnt vmcnt(0) lgkmcnt(0)" ::: "memory");  // gload_lds done
        }
        __builtin_amdgcn_s_barrier();
    }

    // store: s = sl0+wr*128+fm*16+lh*4 (contig 4), o = o0+wc*64+fn*16+lr
    #pragma unroll
    for (int fm = 0; fm < 8; ++fm) {
        int s = sl0 + wr * 128 + fm * 16 + lh * 4;
        #pragma unroll
        for (int fn = 0; fn < 4; ++fn) {
            int o = o0 + wc * 64 + fn * 16 + lr;
            half4 h;
            h[0] = (_Float16)acc[fm][fn][0]; h[1] = (_Float16)acc[fm][fn][1];
            h[2] = (_Float16)acc[fm][fn][2]; h[3] = (_Float16)acc[fm][fn][3];
            *(half4*)(yb + ((size_t)n * BOUT + o) * SLAB + s) = h;
        }
    }
}

// out[slab0+s][c] = bias[c] + sum_{(n,o) in inv[c]} yb[n*512+o][s]
template<int SLAB>
__global__ __launch_bounds__(256) void combine_k(
    const _Float16* __restrict__ yb, const float* __restrict__ bias,
    const int* __restrict__ off, const int* __restrict__ ent,
    int slab0, float* __restrict__ out)
{
    constexpr int SW = (SLAB >= 512) ? 32 : 16;
    const int t = threadIdx.x;
    const int c = blockIdx.x * 16 + (t & 15);
    const int sl0 = blockIdx.y * (16 * SW) + (t >> 4) * SW;
    float acc[SW];
    #pragma unroll
    for (int j = 0; j < SW; ++j) acc[j] = 0.f;
    const int e0 = off[c], e1 = off[c + 1];
    for (int e = e0; e < e1; ++e) {
        int id = ent[e];
        const _Float16* pp = yb + (size_t)id * SLAB + sl0;
        #pragma unroll
        for (int jv = 0; jv < SW / 8; ++jv) {
            half8 v = *(const half8*)(pp + jv * 8);
            #pragma unroll
            for (int q = 0; q < 8; ++q) acc[jv * 8 + q] += (float)v[q];
        }
    }
    const float b = bias[c];
    #pragma unroll
    for (int j = 0; j < SW; ++j)
        out[(size_t)(slab0 + sl0 + j) * OUT_F + c] = acc[j] + b;
}

// ---------------- fallback path (tiny ws): direct atomics into out ----------------
__global__ void init_bias_k(const float* __restrict__ bias, float* __restrict__ out) {
    int i = blockIdx.x * blockDim.x + threadIdx.x;
    f32x4 b = *(const f32x4*)(bias + ((i & 1023) << 2));
    *(f32x4*)(out + (size_t)i * 4) = b;
}

__global__ __launch_bounds__(1024) void gemm_slow_k(
    const float* __restrict__ x, const float* __restrict__ w,
    const int* __restrict__ iin, const int* __restrict__ iout,
    const int* __restrict__ flag, float* __restrict__ out)
{
    __shared__ _Float16 As[128 * 32];
    __shared__ _Float16 Bs[512 * 32];
    __shared__ int kidx[BIN];
    __shared__ int oidx[BOUT];

    const int t = threadIdx.x;
    const int mt = blockIdx.x, n = blockIdx.y;
    const int m0 = mt * 128;
    const int stride = flag[0];

    if (t < BIN) kidx[t] = iin[(n * BIN + t) * stride];
    else         oidx[t - BIN] = iout[(n * BOUT + (t - BIN)) * stride];
    __syncthreads();

    const int lane = t & 63, wid = t >> 6;
    const int wr = wid >> 3, wc = wid & 7;
    const int lr = lane & 15, lh = lane >> 4;

    f32x4 acc[4][4];
    #pragma unroll
    for (int i = 0; i < 4; ++i)
        #pragma unroll
        for (int j = 0; j < 4; ++j) acc[i][j] = (f32x4){0.f, 0.f, 0.f, 0.f};

    char* Asb = (char*)As;
    char* Bsb = (char*)Bs;

    for (int k0 = 0; k0 < BIN; k0 += 32) {
        {
            int m = t >> 3, c4 = (t & 7) * 4;
            const float* xr = x + (size_t)(m0 + m) * IN_F;
            int i0 = kidx[k0 + c4], i1 = kidx[k0 + c4 + 1];
            int i2 = kidx[k0 + c4 + 2], i3 = kidx[k0 + c4 + 3];
            half4 p;
            p[0] = (_Float16)xr[i0]; p[1] = (_Float16)xr[i1];
            p[2] = (_Float16)xr[i2]; p[3] = (_Float16)xr[i3];
            *(half4*)(Asb + m * 64 + ((c4 * 2) ^ (((m >> 1) & 3) << 4))) = p;
        }
        {
            int o = t >> 1, h = t & 1;
            int sw = ((o >> 1) & 3) << 4;
            char* db = Bsb + o * 64;
            const float* src = w + ((size_t)n * BOUT + o) * BIN + k0 + h * 16;
            f32x4 a0 = *(const f32x4*)src;
            f32x4 a1 = *(const f32x4*)(src + 4);
            f32x4 a2 = *(const f32x4*)(src + 8);
            f32x4 a3 = *(const f32x4*)(src + 12);
            half8 p0, p1;
            p0[0] = (_Float16)a0[0]; p0[1] = (_Float16)a0[1];
            p0[2] = (_Float16)a0[2]; p0[3] = (_Float16)a0[3];
            p0[4] = (_Float16)a1[0]; p0[5] = (_Float16)a1[1];
            p0[6] = (_Float16)a1[2]; p0[7] = (_Float16)a1[3];
            p1[0] = (_Float16)a2[0]; p1[1] = (_Float16)a2[1];
            p1[2] = (_Float16)a2[2]; p1[3] = (_Float16)a2[3];
            p1[4] = (_Float16)a3[0]; p1[5] = (_Float16)a3[1];
            p1[6] = (_Float16)a3[2]; p1[7] = (_Float16)a3[3];
            *(half8*)(db + ((h * 32) ^ sw)) = p0;
            *(half8*)(db + ((h * 32 + 16) ^ sw)) = p1;
        }
        __syncthreads();
        {
            half8 a[4], b[4];
            #pragma unroll
            for (int fm = 0; fm < 4; ++fm) {
                int m = wr * 64 + fm * 16 + lr;
                a[fm] = *(const half8*)(Asb + m * 64 + ((lh * 16) ^ (((m >> 1) & 3) << 4)));
            }
            #pragma unroll
            for (int fn = 0; fn < 4; ++fn) {
                int o = wc * 64 + fn * 16 + lr;
                b[fn] = *(const half8*)(Bsb + o * 64 + ((lh * 16) ^ (((o >> 1) & 3) << 4)));
            }
            #pragma unroll
            for (int fm = 0; fm < 4; ++fm)
                #pragma unroll
                for (int fn = 0; fn < 4; ++fn)
                    acc[fm][fn] = __builtin_amdgcn_mfma_f32_16x16x32_f16(
                        a[fm], b[fn], acc[fm][fn], 0, 0, 0);
        }
        __syncthreads();
    }

    int ocol[4];
    #pragma unroll
    for (int fn = 0; fn < 4; ++fn) ocol[fn] = oidx[wc * 64 + fn * 16 + lr];
    #pragma unroll
    for (int fm = 0; fm < 4; ++fm) {
        int rbase = m0 + wr * 64 + fm * 16 + lh * 4;
        #pragma unroll
        for (int fn = 0; fn < 4; ++fn) {
            float* op = out + (size_t)rbase * OUT_F + ocol[fn];
            #pragma unroll
            for (int r = 0; r < 4; ++r)
                atomicAdd(op + (size_t)r * OUT_F, acc[fm][fn][r]);
        }
    }
}

// ---------------- host ----------------

template<int SLAB>
static void run_fast(const float* x, const float* w, const float* bias,
                     const int* iin, const int* iout, float* out,
                     char* ws, hipStream_t stream)
{
    const size_t MB = 1024u * 1024u;
    _Float16* w16  = (_Float16*)ws;                               // 32 MiB
    _Float16* xT16 = (_Float16*)(ws + 32 * MB);                   // 32 MiB
    _Float16* yb   = (_Float16*)(ws + 64 * MB);                   // 64*512*SLAB*2
    const size_t yb_b = (size_t)NBLK * BOUT * SLAB * 2;
    char* meta = ws + 64 * MB + yb_b;
    int* cnt  = (int*)meta;
    int* off  = cnt + 4096;
    int* cur  = off + 4097;
    int* ent  = cur + 4096;
    int* flag = ent + NPAIR;

    detect_stride_k<<<1, 64, 0, stream>>>(iin, flag);
    cvt_w16_k<<<(NBLK * BOUT * BIN) / 1024, 256, 0, stream>>>(w, w16);
    transpose_x_k<<<dim3(IN_F / 64, NROWS / 64), 256, 0, stream>>>(x, xT16);
    hipMemsetAsync(cnt, 0, 4096 * sizeof(int), stream);
    count_k<<<NPAIR / 256, 256, 0, stream>>>(iout, flag, cnt);
    scan_k<<<1, 256, 0, stream>>>(cnt, off, cur);
    fill_k<<<NPAIR / 256, 256, 0, stream>>>(iout, flag, cur, ent);

    constexpr int MT4 = SLAB / 256;
    constexpr int SW = (SLAB >= 512) ? 32 : 16;
    for (int slab0 = 0; slab0 < NROWS; slab0 += SLAB) {
        gemm_fused_k<SLAB><<<dim3(MT4 * 2 * NBLK), 512, 0, stream>>>(
            xT16, w16, iin, flag, slab0, yb);
        combine_k<SLAB><<<dim3(OUT_F / 16, SLAB / (16 * SW)), 256, 0, stream>>>(
            yb, bias, off, ent, slab0, out);
    }
}

extern "C" void kernel_launch(void* const* d_in, const int* in_sizes, int n_in,
                              void* d_out, int out_size, void* d_ws, size_t ws_size,
                              hipStream_t stream) {
    (void)in_sizes; (void)n_in; (void)out_size;
    const float* x    = (const float*)d_in[0];
    const float* w    = (const float*)d_in[1];
    const float* bias = (const float*)d_in[2];
    const int* iin    = (const int*)d_in[3];
    const int* iout   = (const int*)d_in[4];
    float* out        = (float*)d_out;

    const size_t MB = 1024u * 1024u;
    const size_t meta_b = (4096 + 4097 + 4096 + NPAIR + 64) * sizeof(int);
    auto need = [&](size_t slab) { return 64 * MB + (size_t)NBLK * BOUT * slab * 2 + meta_b; };

    if (ws_size >= need(1024)) {
        run_fast<1024>(x, w, bias, iin, iout, out, (char*)d_ws, stream);
    } else if (ws_size >= need(512)) {
        run_fast<512>(x, w, bias, iin, iout, out, (char*)d_ws, stream);
    } else if (ws_size >= need(256)) {
        run_fast<256>(x, w, bias, iin, iout, out, (char*)d_ws, stream);
    } else {
        int* flag = (int*)d_ws;
        detect_stride_k<<<1, 64, 0, stream>>>(iin, flag);
        init_bias_k<<<(size_t)NROWS * OUT_F / 1024, 256, 0, stream>>>(bias, out);
        gemm_slow_k<<<dim3(NROWS / 128, NBLK), 1024, 0, stream>>>(
            x, w, iin, iout, flag, out);
    }
}

// Round 16
// 352.453 us; speedup vs baseline: 1.1469x; 1.1469x over previous
//
#include <hip/hip_runtime.h>

typedef _Float16 half8 __attribute__((ext_vector_type(8)));
typedef _Float16 half4 __attribute__((ext_vector_type(4)));
typedef _Float16 half2v __attribute__((ext_vector_type(2)));
typedef float f32x4 __attribute__((ext_vector_type(4)));

#define IN_F 4096
#define OUT_F 4096
#define NROWS 4096   // B*S
#define NBLK 64
#define BIN 512
#define BOUT 512
#define NPAIR (NBLK * BOUT)   // 32768 (n,o) pairs

__device__ __forceinline__ void gload16(const void* g, void* l) {
    typedef __attribute__((address_space(1))) const void gvoid;
    typedef __attribute__((address_space(3))) void lvoid;
    __builtin_amdgcn_global_load_lds((gvoid*)g, (lvoid*)l, 16, 0, 0);
}

// ---------- setup kernels ----------

__global__ void detect_stride_k(const int* __restrict__ iin, int* __restrict__ flag) {
    int v = iin[threadIdx.x * 2 + 1];
    unsigned long long b = __ballot(v != 0);
    if (threadIdx.x == 0) flag[0] = (b == 0ULL) ? 2 : 1;
}

__global__ void cvt_w16_k(const float* __restrict__ w, _Float16* __restrict__ w16) {
    int i = (blockIdx.x * 256 + threadIdx.x) * 4;
    f32x4 v = *(const f32x4*)(w + i);
    half4 h;
    h[0] = (_Float16)v[0]; h[1] = (_Float16)v[1];
    h[2] = (_Float16)v[2]; h[3] = (_Float16)v[3];
    *(half4*)(w16 + i) = h;
}

// x[s][c] f32 -> xT16[c][s] f16
__global__ __launch_bounds__(256) void transpose_x_k(
    const float* __restrict__ x, _Float16* __restrict__ xT16)
{
    __shared__ float tile[64][65];
    const int c0 = blockIdx.x * 64, s0 = blockIdx.y * 64;
    const int t = threadIdx.x;
    {
        int s = t >> 4, c4 = (t & 15) * 4;
        #pragma unroll
        for (int p = 0; p < 4; ++p) {
            int ss = s + p * 16;
            f32x4 v = *(const f32x4*)(x + (size_t)(s0 + ss) * IN_F + c0 + c4);
            tile[ss][c4 + 0] = v[0]; tile[ss][c4 + 1] = v[1];
            tile[ss][c4 + 2] = v[2]; tile[ss][c4 + 3] = v[3];
        }
    }
    __syncthreads();
    {
        int c = t >> 3, s8 = (t & 7) * 8;
        #pragma unroll
        for (int p = 0; p < 2; ++p) {
            int cc = c + p * 32;
            half8 v;
            #pragma unroll
            for (int q = 0; q < 8; ++q) v[q] = (_Float16)tile[s8 + q][cc];
            *(half8*)(xT16 + (size_t)(c0 + cc) * NROWS + s0 + s8) = v;
        }
    }
}

// ---------- inverse-index build ----------

__global__ void count_k(const int* __restrict__ iout, const int* __restrict__ flag,
                        int* __restrict__ cnt) {
    int i = blockIdx.x * 256 + threadIdx.x;
    int c = iout[(size_t)i * flag[0]];
    atomicAdd(&cnt[c], 1);
}

__global__ __launch_bounds__(256) void scan_k(const int* __restrict__ cnt,
                                              int* __restrict__ off, int* __restrict__ cur) {
    __shared__ int sums[256];
    const int t = threadIdx.x;
    const int base = t * 16;
    int loc[16];
    int s = 0;
    #pragma unroll
    for (int i = 0; i < 16; ++i) { loc[i] = s; s += cnt[base + i]; }
    sums[t] = s;
    __syncthreads();
    for (int d = 1; d < 256; d <<= 1) {
        int v = (t >= d) ? sums[t - d] : 0;
        __syncthreads();
        sums[t] += v;
        __syncthreads();
    }
    int excl = sums[t] - s;
    #pragma unroll
    for (int i = 0; i < 16; ++i) {
        int o = excl + loc[i];
        off[base + i] = o;
        cur[base + i] = o;
    }
    if (t == 255) off[4096] = sums[255];
}

__global__ void fill_k(const int* __restrict__ iout, const int* __restrict__ flag,
                       int* __restrict__ cur, int* __restrict__ ent) {
    int i = blockIdx.x * 256 + threadIdx.x;
    int c = iout[(size_t)i * flag[0]];
    int pos = atomicAdd(&cur[c], 1);
    ent[pos] = i;
}

// ---------- fused gather + dense GEMM (r14-verified body) ----------
// yb[n*512+o][s_loc] = sum_k xT16[iin[n][k]][slab0+s_loc] * w16[n][o][k]
// 256(s) x 256(o) tile, BK=64, 8 waves, double-buffered 128 KiB LDS.
// Waves 0-3: gather-stage A (2 cols x 32 s full-line micro-tile, in-register
// transpose, packed half2 LDS writes); waves 4-7: B staging via gload16.
template<int SLAB>
__global__ __launch_bounds__(512, 2) void gemm_fused_k(
    const _Float16* __restrict__ xT16, const _Float16* __restrict__ w16,
    const int* __restrict__ iin, const int* __restrict__ flag,
    int slab0, _Float16* __restrict__ yb)
{
    __shared__ __align__(1024) _Float16 As[2][256 * 64];   // 2 x 32 KiB
    __shared__ __align__(1024) _Float16 Bs[2][256 * 64];   // 2 x 32 KiB
    __shared__ int kidx[BIN];

    const int t = threadIdx.x;
    const int bid = blockIdx.x;
    constexpr int MT4 = SLAB / 256;
    const int xcd = bid & 7;
    const int r = bid >> 3;
    const int mt = r % MT4;
    const int ot = (r / MT4) & 1;
    const int ng = r / (MT4 * 2);
    const int n = ng * 8 + xcd;                 // n == xcd (mod 8): panels L2-resident
    const int sl0 = mt * 256;                   // slab-local s base (for yb)
    const int sA = slab0 + sl0;                 // absolute s (for xT16)
    const int o0 = ot * 256;

    const int lane = t & 63, wid = t >> 6;      // 8 waves: 2(s) x 4(o) for compute
    const int wr = wid >> 2, wc = wid & 3;
    const int lr = lane & 15, lh = lane >> 4;

    char* Asb = (char*)As;
    char* Bsb = (char*)Bs;

    // load all 512 gather indices once
    kidx[t] = iin[((size_t)n * BIN + t) * flag[0]];
    __syncthreads();

    // A-transposer geometry (waves 0-3, t<256): 2 cols (k=2p,2p+1) x 32 s per thread
    const int p = t & 31;                        // k-pair index 0..31
    const int sb = (t >> 5) & 7;                 // s-block of 32: 0..7
    const _Float16* xsrc = xT16 + sA + sb * 32;
    // B-stager geometry (waves 4-7): u = t&255, 8 gload16 each
    const int u = t & 255;

    // load 2 gathered columns, 32 contiguous s each (one full 64B line per col)
    auto A_LOAD = [&](int ks, half8 v[2][4]) {
        const int c0 = kidx[ks * 64 + 2 * p];
        const int c1 = kidx[ks * 64 + 2 * p + 1];
        const _Float16* s0p = xsrc + (size_t)c0 * NROWS;
        const _Float16* s1p = xsrc + (size_t)c1 * NROWS;
        #pragma unroll
        for (int q = 0; q < 4; ++q) {
            v[0][q] = *(const half8*)(s0p + q * 8);
            v[1][q] = *(const half8*)(s1p + q * 8);
        }
    };
    // transpose and write: s = sb*32 + q*8 + rr, cols k=2p (lo) / 2p+1 (hi) packed.
    // byte = s*128 + ((slot ^ (s&7))<<4) + (k&7)*2, slot = k>>3  [r12-verified]
    auto A_WRITE = [&](int buf, half8 v[2][4]) {
        const int slot = p >> 2;
        const int ib = ((2 * p) & 7) * 2;        // byte offset inside 16B slot
        #pragma unroll
        for (int q = 0; q < 4; ++q)
            #pragma unroll
            for (int rr = 0; rr < 8; ++rr) {
                int s = sb * 32 + q * 8 + rr;
                half2v wv = {v[0][q][rr], v[1][q][rr]};
                *(half2v*)(Asb + buf * 32768 + s * 128 +
                           ((slot ^ (s & 7)) << 4) + ib) = wv;
            }
    };
    auto B_STAGE = [&](int buf, int ks) {
        const int k0 = ks * 64;
        #pragma unroll
        for (int j = 0; j < 8; ++j) {
            int sid = u + j * 256;               // 0..2047
            int row = sid >> 3, sl = sid & 7;
            const char* src = (const char*)(w16 + ((size_t)n * BOUT + o0 + row) * BIN + k0)
                              + ((sl ^ (row & 7)) << 4);
            gload16(src, Bsb + buf * 32768 + sid * 16);
        }
    };

    f32x4 acc[8][4];
    #pragma unroll
    for (int i = 0; i < 8; ++i)
        #pragma unroll
        for (int j = 0; j < 4; ++j) acc[i][j] = (f32x4){0.f, 0.f, 0.f, 0.f};

    // prologue: stage tile 0 into buf 0
    if (wid < 4) {
        half8 v[2][4];
        A_LOAD(0, v);
        A_WRITE(0, v);
    } else {
        B_STAGE(0, 0);
    }
    __syncthreads();

    constexpr int NT = BIN / 64;   // 8 k-tiles

    for (int ks = 0; ks < NT; ++ks) {
        const int cur = ks & 1;
        const int curo = cur * 32768;
        const int nxt = cur ^ 1;

        // 1. issue next-tile staging loads (A: to regs; B: gload16 to LDS)
        half8 v[2][4];
        if (ks < NT - 1) {
            if (wid < 4) A_LOAD(ks + 1, v);
            else         B_STAGE(nxt, ks + 1);
        }

        // 2. compute current tile
        #pragma unroll
        for (int kk = 0; kk < 2; ++kk) {
            half8 a[8], b[4];
            #pragma unroll
            for (int fm = 0; fm < 8; ++fm) {
                int srow = wr * 128 + fm * 16 + lr;
                a[fm] = *(const half8*)(Asb + curo + srow * 128 +
                                        (((kk * 4 + lh) ^ (srow & 7)) << 4));
            }
            #pragma unroll
            for (int fn = 0; fn < 4; ++fn) {
                int orow = wc * 64 + fn * 16 + lr;
                b[fn] = *(const half8*)(Bsb + curo + orow * 128 +
                                        (((kk * 4 + lh) ^ (orow & 7)) << 4));
            }
            __builtin_amdgcn_s_setprio(1);
            #pragma unroll
            for (int fm = 0; fm < 8; ++fm)
                #pragma unroll
                for (int fn = 0; fn < 4; ++fn)
                    acc[fm][fn] = __builtin_amdgcn_mfma_f32_16x16x32_f16(
                        a[fm], b[fn], acc[fm][fn], 0, 0, 0);
            __builtin_amdgcn_s_setprio(0);
        }

        // 3. A-waves: transpose + write next tile (loads had the compute to land)
        if (ks < NT - 1 && wid < 4) A_WRITE(nxt, v);

        __syncthreads();
    }

    // store: s = sl0+wr*128+fm*16+lh*4 (contig 4), o = o0+wc*64+fn*16+lr
    #pragma unroll
    for (int fm = 0; fm < 8; ++fm) {
        int s = sl0 + wr * 128 + fm * 16 + lh * 4;
        #pragma unroll
        for (int fn = 0; fn < 4; ++fn) {
            int o = o0 + wc * 64 + fn * 16 + lr;
            half4 h;
            h[0] = (_Float16)acc[fm][fn][0]; h[1] = (_Float16)acc[fm][fn][1];
            h[2] = (_Float16)acc[fm][fn][2]; h[3] = (_Float16)acc[fm][fn][3];
            *(half4*)(yb + ((size_t)n * BOUT + o) * SLAB + s) = h;
        }
    }
}

// out[slab0+s][c] = bias[c] + sum_{(n,o) in inv[c]} yb[n*512+o][s]
template<int SLAB>
__global__ __launch_bounds__(256) void combine_k(
    const _Float16* __restrict__ yb, const float* __restrict__ bias,
    const int* __restrict__ off, const int* __restrict__ ent,
    int slab0, float* __restrict__ out)
{
    constexpr int SW = (SLAB >= 512) ? 32 : 16;
    const int t = threadIdx.x;
    const int c = blockIdx.x * 16 + (t & 15);
    const int sl0 = blockIdx.y * (16 * SW) + (t >> 4) * SW;
    float acc[SW];
    #pragma unroll
    for (int j = 0; j < SW; ++j) acc[j] = 0.f;
    const int e0 = off[c], e1 = off[c + 1];
    for (int e = e0; e < e1; ++e) {
        int id = ent[e];
        const _Float16* pp = yb + (size_t)id * SLAB + sl0;
        #pragma unroll
        for (int jv = 0; jv < SW / 8; ++jv) {
            half8 v = *(const half8*)(pp + jv * 8);
            #pragma unroll
            for (int q = 0; q < 8; ++q) acc[jv * 8 + q] += (float)v[q];
        }
    }
    const float b = bias[c];
    #pragma unroll
    for (int j = 0; j < SW; ++j)
        out[(size_t)(slab0 + sl0 + j) * OUT_F + c] = acc[j] + b;
}

// ---------------- fallback path (tiny ws): direct atomics into out ----------------
__global__ void init_bias_k(const float* __restrict__ bias, float* __restrict__ out) {
    int i = blockIdx.x * blockDim.x + threadIdx.x;
    f32x4 b = *(const f32x4*)(bias + ((i & 1023) << 2));
    *(f32x4*)(out + (size_t)i * 4) = b;
}

__global__ __launch_bounds__(1024) void gemm_slow_k(
    const float* __restrict__ x, const float* __restrict__ w,
    const int* __restrict__ iin, const int* __restrict__ iout,
    const int* __restrict__ flag, float* __restrict__ out)
{
    __shared__ _Float16 As[128 * 32];
    __shared__ _Float16 Bs[512 * 32];
    __shared__ int kidx[BIN];
    __shared__ int oidx[BOUT];

    const int t = threadIdx.x;
    const int mt = blockIdx.x, n = blockIdx.y;
    const int m0 = mt * 128;
    const int stride = flag[0];

    if (t < BIN) kidx[t] = iin[(n * BIN + t) * stride];
    else         oidx[t - BIN] = iout[(n * BOUT + (t - BIN)) * stride];
    __syncthreads();

    const int lane = t & 63, wid = t >> 6;
    const int wr = wid >> 3, wc = wid & 7;
    const int lr = lane & 15, lh = lane >> 4;

    f32x4 acc[4][4];
    #pragma unroll
    for (int i = 0; i < 4; ++i)
        #pragma unroll
        for (int j = 0; j < 4; ++j) acc[i][j] = (f32x4){0.f, 0.f, 0.f, 0.f};

    char* Asb = (char*)As;
    char* Bsb = (char*)Bs;

    for (int k0 = 0; k0 < BIN; k0 += 32) {
        {
            int m = t >> 3, c4 = (t & 7) * 4;
            const float* xr = x + (size_t)(m0 + m) * IN_F;
            int i0 = kidx[k0 + c4], i1 = kidx[k0 + c4 + 1];
            int i2 = kidx[k0 + c4 + 2], i3 = kidx[k0 + c4 + 3];
            half4 p;
            p[0] = (_Float16)xr[i0]; p[1] = (_Float16)xr[i1];
            p[2] = (_Float16)xr[i2]; p[3] = (_Float16)xr[i3];
            *(half4*)(Asb + m * 64 + ((c4 * 2) ^ (((m >> 1) & 3) << 4))) = p;
        }
        {
            int o = t >> 1, h = t & 1;
            int sw = ((o >> 1) & 3) << 4;
            char* db = Bsb + o * 64;
            const float* src = w + ((size_t)n * BOUT + o) * BIN + k0 + h * 16;
            f32x4 a0 = *(const f32x4*)src;
            f32x4 a1 = *(const f32x4*)(src + 4);
            f32x4 a2 = *(const f32x4*)(src + 8);
            f32x4 a3 = *(const f32x4*)(src + 12);
            half8 p0, p1;
            p0[0] = (_Float16)a0[0]; p0[1] = (_Float16)a0[1];
            p0[2] = (_Float16)a0[2]; p0[3] = (_Float16)a0[3];
            p0[4] = (_Float16)a1[0]; p0[5] = (_Float16)a1[1];
            p0[6] = (_Float16)a1[2]; p0[7] = (_Float16)a1[3];
            p1[0] = (_Float16)a2[0]; p1[1] = (_Float16)a2[1];
            p1[2] = (_Float16)a2[2]; p1[3] = (_Float16)a2[3];
            p1[4] = (_Float16)a3[0]; p1[5] = (_Float16)a3[1];
            p1[6] = (_Float16)a3[2]; p1[7] = (_Float16)a3[3];
            *(half8*)(db + ((h * 32) ^ sw)) = p0;
            *(half8*)(db + ((h * 32 + 16) ^ sw)) = p1;
        }
        __syncthreads();
        {
            half8 a[4], b[4];
            #pragma unroll
            for (int fm = 0; fm < 4; ++fm) {
                int m = wr * 64 + fm * 16 + lr;
                a[fm] = *(const half8*)(Asb + m * 64 + ((lh * 16) ^ (((m >> 1) & 3) << 4)));
            }
            #pragma unroll
            for (int fn = 0; fn < 4; ++fn) {
                int o = wc * 64 + fn * 16 + lr;
                b[fn] = *(const half8*)(Bsb + o * 64 + ((lh * 16) ^ (((o >> 1) & 3) << 4)));
            }
            #pragma unroll
            for (int fm = 0; fm < 4; ++fm)
                #pragma unroll
                for (int fn = 0; fn < 4; ++fn)
                    acc[fm][fn] = __builtin_amdgcn_mfma_f32_16x16x32_f16(
                        a[fm], b[fn], acc[fm][fn], 0, 0, 0);
        }
        __syncthreads();
    }

    int ocol[4];
    #pragma unroll
    for (int fn = 0; fn < 4; ++fn) ocol[fn] = oidx[wc * 64 + fn * 16 + lr];
    #pragma unroll
    for (int fm = 0; fm < 4; ++fm) {
        int rbase = m0 + wr * 64 + fm * 16 + lh * 4;
        #pragma unroll
        for (int fn = 0; fn < 4; ++fn) {
            float* op = out + (size_t)rbase * OUT_F + ocol[fn];
            #pragma unroll
            for (int r = 0; r < 4; ++r)
                atomicAdd(op + (size_t)r * OUT_F, acc[fm][fn][r]);
        }
    }
}

// ---------------- host ----------------

template<int SLAB>
static void run_fast(const float* x, const float* w, const float* bias,
                     const int* iin, const int* iout, float* out,
                     char* ws, hipStream_t stream)
{
    const size_t MB = 1024u * 1024u;
    _Float16* w16  = (_Float16*)ws;                               // 32 MiB
    _Float16* xT16 = (_Float16*)(ws + 32 * MB);                   // 32 MiB
    _Float16* yb   = (_Float16*)(ws + 64 * MB);                   // 64*512*SLAB*2
    const size_t yb_b = (size_t)NBLK * BOUT * SLAB * 2;
    char* meta = ws + 64 * MB + yb_b;
    int* cnt  = (int*)meta;
    int* off  = cnt + 4096;
    int* cur  = off + 4097;
    int* ent  = cur + 4096;
    int* flag = ent + NPAIR;

    detect_stride_k<<<1, 64, 0, stream>>>(iin, flag);
    cvt_w16_k<<<(NBLK * BOUT * BIN) / 1024, 256, 0, stream>>>(w, w16);
    transpose_x_k<<<dim3(IN_F / 64, NROWS / 64), 256, 0, stream>>>(x, xT16);
    hipMemsetAsync(cnt, 0, 4096 * sizeof(int), stream);
    count_k<<<NPAIR / 256, 256, 0, stream>>>(iout, flag, cnt);
    scan_k<<<1, 256, 0, stream>>>(cnt, off, cur);
    fill_k<<<NPAIR / 256, 256, 0, stream>>>(iout, flag, cur, ent);

    constexpr int MT4 = SLAB / 256;
    constexpr int SW = (SLAB >= 512) ? 32 : 16;
    for (int slab0 = 0; slab0 < NROWS; slab0 += SLAB) {
        gemm_fused_k<SLAB><<<dim3(MT4 * 2 * NBLK), 512, 0, stream>>>(
            xT16, w16, iin, flag, slab0, yb);
        combine_k<SLAB><<<dim3(OUT_F / 16, SLAB / (16 * SW)), 256, 0, stream>>>(
            yb, bias, off, ent, slab0, out);
    }
}

extern "C" void kernel_launch(void* const* d_in, const int* in_sizes, int n_in,
                              void* d_out, int out_size, void* d_ws, size_t ws_size,
                              hipStream_t stream) {
    (void)in_sizes; (void)n_in; (void)out_size;
    const float* x    = (const float*)d_in[0];
    const float* w    = (const float*)d_in[1];
    const float* bias = (const float*)d_in[2];
    const int* iin    = (const int*)d_in[3];
    const int* iout   = (const int*)d_in[4];
    float* out        = (float*)d_out;

    const size_t MB = 1024u * 1024u;
    const size_t meta_b = (4096 + 4097 + 4096 + NPAIR + 64) * sizeof(int);
    auto need = [&](size_t slab) { return 64 * MB + (size_t)NBLK * BOUT * slab * 2 + meta_b; };

    if (ws_size >= need(2048)) {
        run_fast<2048>(x, w, bias, iin, iout, out, (char*)d_ws, stream);
    } else if (ws_size >= need(1024)) {
        run_fast<1024>(x, w, bias, iin, iout, out, (char*)d_ws, stream);
    } else if (ws_size >= need(512)) {
        run_fast<512>(x, w, bias, iin, iout, out, (char*)d_ws, stream);
    } else if (ws_size >= need(256)) {
        run_fast<256>(x, w, bias, iin, iout, out, (char*)d_ws, stream);
    } else {
        int* flag = (int*)d_ws;
        detect_stride_k<<<1, 64, 0, stream>>>(iin, flag);
        init_bias_k<<<(size_t)NROWS * OUT_F / 1024, 256, 0, stream>>>(bias, out);
        gemm_slow_k<<<dim3(NROWS / 128, NBLK), 1024, 0, stream>>>(
            x, w, iin, iout, flag, out);
    }
}